// Round 1
// baseline (423.835 us; speedup 1.0000x reference)
//
#include <hip/hip_runtime.h>

typedef __attribute__((ext_vector_type(8))) short bf16x8;
typedef __attribute__((ext_vector_type(4))) float f32x4;

#define GLD_LDS16(g, l)                                                        \
  __builtin_amdgcn_global_load_lds(                                            \
      (const __attribute__((address_space(1))) void*)(g),                      \
      (__attribute__((address_space(3))) void*)(l), 16, 0, 0)

__device__ __forceinline__ f32x4 mfma_bf16(bf16x8 a, bf16x8 b, f32x4 c) {
  return __builtin_amdgcn_mfma_f32_16x16x32_bf16(a, b, c, 0, 0, 0);
}

__device__ __forceinline__ unsigned short f2bf(float f) {
  union { float f; unsigned int u; } a;
  a.f = f;
  unsigned int u = a.u;
  unsigned int r = (u + 0x7fffu + ((u >> 16) & 1u)) >> 16;
  return (unsigned short)r;
}

// ---------------- prep kernels ----------------

__global__ void k_convert(const float* __restrict__ in,
                          unsigned short* __restrict__ out, int n8) {
  int i = blockIdx.x * 256 + threadIdx.x;
  if (i >= n8) return;
  const float4* p = reinterpret_cast<const float4*>(in) + (size_t)i * 2;
  float4 a = p[0], b = p[1];
  union { unsigned short u[8]; uint4 v; } pk;
  pk.u[0] = f2bf(a.x); pk.u[1] = f2bf(a.y); pk.u[2] = f2bf(a.z); pk.u[3] = f2bf(a.w);
  pk.u[4] = f2bf(b.x); pk.u[5] = f2bf(b.y); pk.u[6] = f2bf(b.z); pk.u[7] = f2bf(b.w);
  reinterpret_cast<uint4*>(out)[i] = pk.v;
}

// out[c][r] = in[r][c], in: [R][C] f32, out: [C][R] bf16
__global__ void k_transpose(const float* __restrict__ in,
                            unsigned short* __restrict__ out, int R, int C) {
  __shared__ float tile[32][33];
  int c0 = blockIdx.x * 32, r0 = blockIdx.y * 32;
  int tx = threadIdx.x, ty = threadIdx.y;
#pragma unroll
  for (int j = 0; j < 4; ++j)
    tile[ty + j * 8][tx] = in[(size_t)(r0 + ty + j * 8) * C + (c0 + tx)];
  __syncthreads();
#pragma unroll
  for (int j = 0; j < 4; ++j)
    out[(size_t)(c0 + ty + j * 8) * R + (r0 + tx)] = f2bf(tile[tx][ty + j * 8]);
}

__global__ void k_bias_concat(const float* __restrict__ bq,
                              const float* __restrict__ bk,
                              const float* __restrict__ bv,
                              float* __restrict__ o) {
  int i = blockIdx.x * 256 + threadIdx.x;
  if (i < 2048) o[i] = bq[i];
  else if (i < 2176) o[i] = bk[i - 2048];
  else if (i < 2304) o[i] = bv[i - 2176];
}

// ---------------- GEMM: C[M][N] = A[M][K] * Bt[N][K]^T + bias ----------------

template <bool OUT_F32>
__global__ __launch_bounds__(256, 2) void k_gemm(
    const unsigned short* __restrict__ A, const unsigned short* __restrict__ Bt,
    const float* __restrict__ bias, void* __restrict__ Cp, int M, int N, int K) {
  __shared__ __align__(16) unsigned short lda[128 * 32];
  __shared__ __align__(16) unsigned short ldb[128 * 32];
  const int t = threadIdx.x;
  const int l = t & 63;
  const int w = t >> 6;
  const int wr = w >> 1, wc = w & 1;
  const int lr = l & 15, lg = l >> 4;
  const int m0 = blockIdx.y * 128, n0 = blockIdx.x * 128;

  f32x4 acc[4][4] = {};

  for (int kt = 0; kt < K; kt += 32) {
#pragma unroll
    for (int c = 0; c < 2; ++c) {
      int idx = t * 8 + c * 2048;
      int row = idx >> 5, col = idx & 31;
      GLD_LDS16(A + (size_t)(m0 + row) * K + kt + col, lda + w * 512 + c * 2048);
      GLD_LDS16(Bt + (size_t)(n0 + row) * K + kt + col, ldb + w * 512 + c * 2048);
    }
    __syncthreads();
    bf16x8 af[4], bfr[4];
#pragma unroll
    for (int i = 0; i < 4; ++i)
      af[i] = *reinterpret_cast<const bf16x8*>(lda + (wr * 64 + i * 16 + lr) * 32 + lg * 8);
#pragma unroll
    for (int j = 0; j < 4; ++j)
      bfr[j] = *reinterpret_cast<const bf16x8*>(ldb + (wc * 64 + j * 16 + lr) * 32 + lg * 8);
#pragma unroll
    for (int i = 0; i < 4; ++i)
#pragma unroll
      for (int j = 0; j < 4; ++j)
        acc[i][j] = mfma_bf16(af[i], bfr[j], acc[i][j]);
    __syncthreads();
  }

#pragma unroll
  for (int j = 0; j < 4; ++j) {
    int col = n0 + wc * 64 + j * 16 + lr;
    float bv = bias[col];
#pragma unroll
    for (int i = 0; i < 4; ++i) {
      int rowb = m0 + wr * 64 + i * 16 + lg * 4;
#pragma unroll
      for (int r = 0; r < 4; ++r) {
        float v = acc[i][j][r] + bv;
        if (OUT_F32)
          reinterpret_cast<float*>(Cp)[(size_t)(rowb + r) * N + col] = v;
        else
          reinterpret_cast<unsigned short*>(Cp)[(size_t)(rowb + r) * N + col] = f2bf(v);
      }
    }
  }
}

// ---------------- flash attention ----------------
// qkv: [4096][2304] bf16 (Q: cols h*128+d, K: 2048+d, V: 2176+d)
// out: [4096][2048] bf16, layout [b*2048+s][h*128+d]

__global__ __launch_bounds__(256, 2) void k_attn(
    const unsigned short* __restrict__ qkv, unsigned short* __restrict__ out) {
  __shared__ __align__(16) unsigned short q_lds[128 * 128];  // reused as p_lds[128][72]
  __shared__ __align__(16) unsigned short k_lds[64 * 128];   // xor-swizzled 16B units
  __shared__ __align__(16) unsigned short v_lds[128 * 72];   // V^T, padded
  unsigned short* p_lds = q_lds;

  const int t = threadIdx.x, l = t & 63, w = t >> 6;
  const int lr = l & 15, lg = l >> 4;
  const int bid = blockIdx.x;
  const int qt = bid & 15, h = (bid >> 4) & 15, b = bid >> 8;
  const size_t rowQ0 = (size_t)b * 2048 + qt * 128;
  const size_t rowK0 = (size_t)b * 2048;

  // stage Q tile [128][128] linear
#pragma unroll
  for (int c = 0; c < 8; ++c) {
    int f16 = t + c * 256;
    int row = f16 >> 4, col16 = f16 & 15;
    GLD_LDS16(qkv + (rowQ0 + row) * 2304 + h * 128 + col16 * 8,
              q_lds + w * 512 + c * 2048);
  }
  __syncthreads();

  bf16x8 qf[2][4];
#pragma unroll
  for (int rt = 0; rt < 2; ++rt)
#pragma unroll
    for (int kd = 0; kd < 4; ++kd)
      qf[rt][kd] = *reinterpret_cast<const bf16x8*>(
          q_lds + (w * 32 + rt * 16 + lr) * 128 + kd * 32 + lg * 8);

  f32x4 o_acc[2][8] = {};
  float m_s[2][4], l_s[2][4];
#pragma unroll
  for (int rt = 0; rt < 2; ++rt)
#pragma unroll
    for (int r = 0; r < 4; ++r) { m_s[rt][r] = -1e30f; l_s[rt][r] = 0.f; }

  const float C_SM = 0.08838834764831845f * 1.4426950408889634f;

  for (int kc = 0; kc < 32; ++kc) {
    // stage K chunk [64][128], source pre-swizzled so swizzled-read is conflict-free
#pragma unroll
    for (int c = 0; c < 4; ++c) {
      int f16 = t + c * 256;
      int row = f16 >> 4;
      int col16 = (f16 & 15) ^ (row & 7);
      GLD_LDS16(qkv + (rowK0 + kc * 64 + row) * 2304 + 2048 + col16 * 8,
                k_lds + w * 512 + c * 2048);
    }
    // stage V chunk transposed: v_lds[d][i] = V[i][d]
#pragma unroll
    for (int c = 0; c < 4; ++c) {
      int i = l;
      int d0 = w * 32 + c * 8;
      bf16x8 vv = *reinterpret_cast<const bf16x8*>(
          qkv + (rowK0 + kc * 64 + i) * 2304 + 2176 + d0);
#pragma unroll
      for (int e = 0; e < 8; ++e)
        v_lds[(d0 + e) * 72 + i] = (unsigned short)vv[e];
    }
    __syncthreads();

    // S = Q K^T (per wave: 32 q-rows x 64 kk)
    f32x4 sf[2][4];
#pragma unroll
    for (int ctK = 0; ctK < 4; ++ctK) {
      f32x4 s0 = {0.f, 0.f, 0.f, 0.f}, s1 = {0.f, 0.f, 0.f, 0.f};
#pragma unroll
      for (int kd = 0; kd < 4; ++kd) {
        int row = ctK * 16 + lr;
        int u = (kd * 4 + lg) ^ (row & 7);
        bf16x8 kf = *reinterpret_cast<const bf16x8*>(k_lds + row * 128 + u * 8);
        s0 = mfma_bf16(qf[0][kd], kf, s0);
        s1 = mfma_bf16(qf[1][kd], kf, s1);
      }
      sf[0][ctK] = s0; sf[1][ctK] = s1;
    }

    // online softmax (rows live across the 16 lanes sharing lg)
#pragma unroll
    for (int rt = 0; rt < 2; ++rt) {
#pragma unroll
      for (int r = 0; r < 4; ++r) {
        float v = fmaxf(fmaxf(sf[rt][0][r], sf[rt][1][r]),
                        fmaxf(sf[rt][2][r], sf[rt][3][r]));
        v = fmaxf(v, __shfl_xor(v, 1));
        v = fmaxf(v, __shfl_xor(v, 2));
        v = fmaxf(v, __shfl_xor(v, 4));
        v = fmaxf(v, __shfl_xor(v, 8));
        float newm = fmaxf(m_s[rt][r], v);
        float alpha = __builtin_amdgcn_exp2f((m_s[rt][r] - newm) * C_SM);
        m_s[rt][r] = newm;
        float psum = 0.f;
#pragma unroll
        for (int ctK = 0; ctK < 4; ++ctK) {
          float p = __builtin_amdgcn_exp2f((sf[rt][ctK][r] - newm) * C_SM);
          sf[rt][ctK][r] = p;
          psum += p;
        }
        psum += __shfl_xor(psum, 1);
        psum += __shfl_xor(psum, 2);
        psum += __shfl_xor(psum, 4);
        psum += __shfl_xor(psum, 8);
        l_s[rt][r] = l_s[rt][r] * alpha + psum;
#pragma unroll
        for (int ct8 = 0; ct8 < 8; ++ct8) o_acc[rt][ct8][r] *= alpha;
      }
      // write P (wave-local rows)
#pragma unroll
      for (int ctK = 0; ctK < 4; ++ctK)
#pragma unroll
        for (int r = 0; r < 4; ++r)
          p_lds[(w * 32 + rt * 16 + lg * 4 + r) * 72 + ctK * 16 + lr] =
              f2bf(sf[rt][ctK][r]);
    }

    // O += P V
#pragma unroll
    for (int ks = 0; ks < 2; ++ks) {
      bf16x8 pf[2];
#pragma unroll
      for (int rt = 0; rt < 2; ++rt)
        pf[rt] = *reinterpret_cast<const bf16x8*>(
            p_lds + (w * 32 + rt * 16 + lr) * 72 + ks * 32 + lg * 8);
#pragma unroll
      for (int ct8 = 0; ct8 < 8; ++ct8) {
        bf16x8 vf = *reinterpret_cast<const bf16x8*>(
            v_lds + (ct8 * 16 + lr) * 72 + ks * 32 + lg * 8);
        o_acc[0][ct8] = mfma_bf16(pf[0], vf, o_acc[0][ct8]);
        o_acc[1][ct8] = mfma_bf16(pf[1], vf, o_acc[1][ct8]);
      }
    }
    __syncthreads();
  }

  // epilogue: normalize, write bf16
#pragma unroll
  for (int rt = 0; rt < 2; ++rt) {
    float inv[4];
#pragma unroll
    for (int r = 0; r < 4; ++r) inv[r] = 1.0f / l_s[rt][r];
#pragma unroll
    for (int ct8 = 0; ct8 < 8; ++ct8) {
      int col = h * 128 + ct8 * 16 + lr;
#pragma unroll
      for (int r = 0; r < 4; ++r) {
        size_t row = rowQ0 + w * 32 + rt * 16 + lg * 4 + r;
        out[row * 2048 + col] = f2bf(o_acc[rt][ct8][r] * inv[r]);
      }
    }
  }
}

// ---------------- launch ----------------

extern "C" void kernel_launch(void* const* d_in, const int* in_sizes, int n_in,
                              void* d_out, int out_size, void* d_ws,
                              size_t ws_size, hipStream_t stream) {
  const float* x  = (const float*)d_in[0];
  const float* wq = (const float*)d_in[2];
  const float* bq = (const float*)d_in[3];
  const float* wk = (const float*)d_in[4];
  const float* bk = (const float*)d_in[5];
  const float* wv = (const float*)d_in[6];
  const float* bv = (const float*)d_in[7];
  const float* wo = (const float*)d_in[8];
  const float* bo = (const float*)d_in[9];
  float* out = (float*)d_out;

  char* ws = (char*)d_ws;
  unsigned short* xb    = (unsigned short*)(ws);                       // 16.8MB [4096][2048] (reused as attn out)
  unsigned short* wqkvT = (unsigned short*)(ws + 16777216);            // 9.4MB  [2304][2048]
  unsigned short* woT   = (unsigned short*)(ws + 26214400);            // 8.4MB  [2048][2048]
  unsigned short* qkvb  = (unsigned short*)(ws + 34603008);            // 18.9MB [4096][2304]
  float*          biasq = (float*)(ws + 53477376);                     // 9.2KB

  k_convert<<<4096, 256, 0, stream>>>(x, xb, 1048576);
  k_transpose<<<dim3(64, 64), dim3(32, 8), 0, stream>>>(wq, wqkvT, 2048, 2048);
  k_transpose<<<dim3(4, 64),  dim3(32, 8), 0, stream>>>(wk, wqkvT + (size_t)2048 * 2048, 2048, 128);
  k_transpose<<<dim3(4, 64),  dim3(32, 8), 0, stream>>>(wv, wqkvT + (size_t)2176 * 2048, 2048, 128);
  k_transpose<<<dim3(64, 64), dim3(32, 8), 0, stream>>>(wo, woT, 2048, 2048);
  k_bias_concat<<<9, 256, 0, stream>>>(bq, bk, bv, biasq);

  k_gemm<false><<<dim3(18, 32), 256, 0, stream>>>(xb, wqkvT, biasq, qkvb, 4096, 2304, 2048);
  k_attn<<<512, 256, 0, stream>>>(qkvb, xb);
  k_gemm<true><<<dim3(16, 32), 256, 0, stream>>>(xb, woT, bo, out, 4096, 2048, 2048);
}

// Round 2
// 414.835 us; speedup vs baseline: 1.0217x; 1.0217x over previous
//
#include <hip/hip_runtime.h>

typedef __attribute__((ext_vector_type(8))) short bf16x8;
typedef __attribute__((ext_vector_type(4))) float f32x4;

#define GLD_LDS16(g, l)                                                        \
  __builtin_amdgcn_global_load_lds(                                            \
      (const __attribute__((address_space(1))) void*)(g),                      \
      (__attribute__((address_space(3))) void*)(l), 16, 0, 0)

__device__ __forceinline__ f32x4 mfma_bf16(bf16x8 a, bf16x8 b, f32x4 c) {
  return __builtin_amdgcn_mfma_f32_16x16x32_bf16(a, b, c, 0, 0, 0);
}

__device__ __forceinline__ unsigned short f2bf(float f) {
  union { float f; unsigned int u; } a;
  a.f = f;
  unsigned int u = a.u;
  unsigned int r = (u + 0x7fffu + ((u >> 16) & 1u)) >> 16;
  return (unsigned short)r;
}

// ---------------- prep kernels ----------------

__global__ void k_convert(const float* __restrict__ in,
                          unsigned short* __restrict__ out, int n8) {
  int i = blockIdx.x * 256 + threadIdx.x;
  if (i >= n8) return;
  const float4* p = reinterpret_cast<const float4*>(in) + (size_t)i * 2;
  float4 a = p[0], b = p[1];
  union { unsigned short u[8]; uint4 v; } pk;
  pk.u[0] = f2bf(a.x); pk.u[1] = f2bf(a.y); pk.u[2] = f2bf(a.z); pk.u[3] = f2bf(a.w);
  pk.u[4] = f2bf(b.x); pk.u[5] = f2bf(b.y); pk.u[6] = f2bf(b.z); pk.u[7] = f2bf(b.w);
  reinterpret_cast<uint4*>(out)[i] = pk.v;
}

// out[c][r] = in[r][c], in: [R][C] f32, out: [C][R] bf16
__global__ void k_transpose(const float* __restrict__ in,
                            unsigned short* __restrict__ out, int R, int C) {
  __shared__ float tile[32][33];
  int c0 = blockIdx.x * 32, r0 = blockIdx.y * 32;
  int tx = threadIdx.x, ty = threadIdx.y;
#pragma unroll
  for (int j = 0; j < 4; ++j)
    tile[ty + j * 8][tx] = in[(size_t)(r0 + ty + j * 8) * C + (c0 + tx)];
  __syncthreads();
#pragma unroll
  for (int j = 0; j < 4; ++j)
    out[(size_t)(c0 + ty + j * 8) * R + (r0 + tx)] = f2bf(tile[tx][ty + j * 8]);
}

__global__ void k_bias_concat(const float* __restrict__ bq,
                              const float* __restrict__ bk,
                              const float* __restrict__ bv,
                              float* __restrict__ o) {
  int i = blockIdx.x * 256 + threadIdx.x;
  if (i < 2048) o[i] = bq[i];
  else if (i < 2176) o[i] = bk[i - 2048];
  else if (i < 2304) o[i] = bv[i - 2176];
}

// ---------------- GEMM: C[M][N] = A[M][K] * Bt[N][K]^T + bias ----------------

template <bool OUT_F32>
__global__ __launch_bounds__(256, 2) void k_gemm(
    const unsigned short* __restrict__ A, const unsigned short* __restrict__ Bt,
    const float* __restrict__ bias, void* __restrict__ Cp, int M, int N, int K) {
  __shared__ __align__(16) unsigned short lda[128 * 32];
  __shared__ __align__(16) unsigned short ldb[128 * 32];
  const int t = threadIdx.x;
  const int l = t & 63;
  const int w = t >> 6;
  const int wr = w >> 1, wc = w & 1;
  const int lr = l & 15, lg = l >> 4;
  const int m0 = blockIdx.y * 128, n0 = blockIdx.x * 128;

  f32x4 acc[4][4] = {};

  for (int kt = 0; kt < K; kt += 32) {
#pragma unroll
    for (int c = 0; c < 2; ++c) {
      int idx = t * 8 + c * 2048;
      int row = idx >> 5, col = idx & 31;
      GLD_LDS16(A + (size_t)(m0 + row) * K + kt + col, lda + w * 512 + c * 2048);
      GLD_LDS16(Bt + (size_t)(n0 + row) * K + kt + col, ldb + w * 512 + c * 2048);
    }
    __syncthreads();
    bf16x8 af[4], bfr[4];
#pragma unroll
    for (int i = 0; i < 4; ++i)
      af[i] = *reinterpret_cast<const bf16x8*>(lda + (wr * 64 + i * 16 + lr) * 32 + lg * 8);
#pragma unroll
    for (int j = 0; j < 4; ++j)
      bfr[j] = *reinterpret_cast<const bf16x8*>(ldb + (wc * 64 + j * 16 + lr) * 32 + lg * 8);
#pragma unroll
    for (int i = 0; i < 4; ++i)
#pragma unroll
      for (int j = 0; j < 4; ++j)
        acc[i][j] = mfma_bf16(af[i], bfr[j], acc[i][j]);
    __syncthreads();
  }

#pragma unroll
  for (int j = 0; j < 4; ++j) {
    int col = n0 + wc * 64 + j * 16 + lr;
    float bv = bias[col];
#pragma unroll
    for (int i = 0; i < 4; ++i) {
      int rowb = m0 + wr * 64 + i * 16 + lg * 4;
#pragma unroll
      for (int r = 0; r < 4; ++r) {
        float v = acc[i][j][r] + bv;
        if (OUT_F32)
          reinterpret_cast<float*>(Cp)[(size_t)(rowb + r) * N + col] = v;
        else
          reinterpret_cast<unsigned short*>(Cp)[(size_t)(rowb + r) * N + col] = f2bf(v);
      }
    }
  }
}

// ---------------- flash attention (8 waves, dbuf K, reg-staged V) ----------------
// qkv: [4096][2304] bf16 (Q: cols h*128+d, K: 2048+d, V: 2176+d)
// out: [4096][2048] bf16, layout [b*2048+s][h*128+d]

__global__ __launch_bounds__(512, 4) void k_attn(
    const unsigned short* __restrict__ qkv, unsigned short* __restrict__ out) {
  __shared__ __align__(16) unsigned short k_lds[2][64 * 128];  // xor-swizzled 16B units
  __shared__ __align__(16) unsigned short v_lds[128 * 68];     // V^T, padded 68
  __shared__ __align__(16) unsigned short p_lds[128 * 72];     // P, padded 72

  const int t = threadIdx.x, l = t & 63, w = t >> 6;
  const int lr = l & 15, lg = l >> 4;
  const int bid = blockIdx.x;
  const int qt = bid & 15, h = (bid >> 4) & 15, b = bid >> 8;
  const size_t rowQ0 = (size_t)b * 2048 + qt * 128;
  const size_t rowK0 = (size_t)b * 2048;

  // Q fragments direct from global (one-time): wave w owns q-rows w*16..w*16+15
  bf16x8 qf[4];
  {
    const unsigned short* qrow = qkv + (rowQ0 + w * 16 + lr) * 2304 + h * 128;
#pragma unroll
    for (int kd = 0; kd < 4; ++kd)
      qf[kd] = *reinterpret_cast<const bf16x8*>(qrow + kd * 32 + lg * 8);
  }

  // prologue: stage K chunk 0 (swizzled source -> linear LDS), V chunk 0
#pragma unroll
  for (int c = 0; c < 2; ++c) {
    int f16 = t + c * 512;
    int row = f16 >> 4;
    int col16 = (f16 & 15) ^ (row & 7);
    GLD_LDS16(qkv + (rowK0 + row) * 2304 + 2048 + col16 * 8,
              &k_lds[0][0] + w * 512 + c * 4096);
  }
  bf16x8 vst[2];
#pragma unroll
  for (int c = 0; c < 2; ++c)
    vst[c] = *reinterpret_cast<const bf16x8*>(
        qkv + (rowK0 + l) * 2304 + 2176 + w * 16 + c * 8);
#pragma unroll
  for (int c = 0; c < 2; ++c)
#pragma unroll
    for (int e = 0; e < 8; ++e)
      v_lds[(w * 16 + c * 8 + e) * 68 + l] = (unsigned short)vst[c][e];
  __syncthreads();

  f32x4 o_acc[8] = {};
  float m_s[4], l_s[4];
#pragma unroll
  for (int r = 0; r < 4; ++r) { m_s[r] = -1e30f; l_s[r] = 0.f; }

  const float C_SM = 0.08838834764831845f * 1.4426950408889634f;

  for (int kc = 0; kc < 32; ++kc) {
    const int cur = kc & 1;
    const unsigned short* kl = &k_lds[cur][0];

    if (kc < 31) {
      // issue next K chunk into other buffer (latency hides under compute)
#pragma unroll
      for (int c = 0; c < 2; ++c) {
        int f16 = t + c * 512;
        int row = f16 >> 4;
        int col16 = (f16 & 15) ^ (row & 7);
        GLD_LDS16(qkv + (rowK0 + (kc + 1) * 64 + row) * 2304 + 2048 + col16 * 8,
                  &k_lds[cur ^ 1][0] + w * 512 + c * 4096);
      }
      // issue next V chunk into regs (ds_write after barrier)
#pragma unroll
      for (int c = 0; c < 2; ++c)
        vst[c] = *reinterpret_cast<const bf16x8*>(
            qkv + (rowK0 + (kc + 1) * 64 + l) * 2304 + 2176 + w * 16 + c * 8);
    }

    // S = Q K^T (wave: 16 q-rows x 64 kk)
    f32x4 sf[4];
#pragma unroll
    for (int ctK = 0; ctK < 4; ++ctK) {
      f32x4 s = {0.f, 0.f, 0.f, 0.f};
#pragma unroll
      for (int kd = 0; kd < 4; ++kd) {
        int row = ctK * 16 + lr;
        int u = (kd * 4 + lg) ^ (row & 7);
        bf16x8 kf = *reinterpret_cast<const bf16x8*>(kl + row * 128 + u * 8);
        s = mfma_bf16(qf[kd], kf, s);
      }
      sf[ctK] = s;
    }

    // online softmax (row q = w*16 + lg*4 + r; reduce over the 16 lr lanes)
#pragma unroll
    for (int r = 0; r < 4; ++r) {
      float v = fmaxf(fmaxf(sf[0][r], sf[1][r]), fmaxf(sf[2][r], sf[3][r]));
      v = fmaxf(v, __shfl_xor(v, 1));
      v = fmaxf(v, __shfl_xor(v, 2));
      v = fmaxf(v, __shfl_xor(v, 4));
      v = fmaxf(v, __shfl_xor(v, 8));
      if (!__all(v <= m_s[r])) {  // defer/skip rescale when no row grew
        float newm = fmaxf(m_s[r], v);
        float alpha = __builtin_amdgcn_exp2f((m_s[r] - newm) * C_SM);
        m_s[r] = newm;
        l_s[r] *= alpha;
#pragma unroll
        for (int ct8 = 0; ct8 < 8; ++ct8) o_acc[ct8][r] *= alpha;
      }
      float psum = 0.f;
#pragma unroll
      for (int ctK = 0; ctK < 4; ++ctK) {
        float p = __builtin_amdgcn_exp2f((sf[ctK][r] - m_s[r]) * C_SM);
        sf[ctK][r] = p;
        psum += p;
      }
      psum += __shfl_xor(psum, 1);
      psum += __shfl_xor(psum, 2);
      psum += __shfl_xor(psum, 4);
      psum += __shfl_xor(psum, 8);
      l_s[r] += psum;
    }

    // write P (wave-private 16-row slab)
#pragma unroll
    for (int ctK = 0; ctK < 4; ++ctK)
#pragma unroll
      for (int r = 0; r < 4; ++r)
        p_lds[(w * 16 + lg * 4 + r) * 72 + ctK * 16 + lr] = f2bf(sf[ctK][r]);

    // O += P V
#pragma unroll
    for (int ks = 0; ks < 2; ++ks) {
      bf16x8 pf = *reinterpret_cast<const bf16x8*>(
          p_lds + (w * 16 + lr) * 72 + ks * 32 + lg * 8);
#pragma unroll
      for (int ct8 = 0; ct8 < 8; ++ct8) {
        bf16x8 vf = *reinterpret_cast<const bf16x8*>(
            v_lds + (ct8 * 16 + lr) * 68 + ks * 32 + lg * 8);
        o_acc[ct8] = mfma_bf16(pf, vf, o_acc[ct8]);
      }
    }

    __syncthreads();  // everyone done reading v_lds (also drains vmcnt: K-next in)
    if (kc < 31) {
#pragma unroll
      for (int c = 0; c < 2; ++c)
#pragma unroll
        for (int e = 0; e < 8; ++e)
          v_lds[(w * 16 + c * 8 + e) * 68 + l] = (unsigned short)vst[c][e];
    }
    __syncthreads();  // v_lds (and k_lds[nxt]) ready
  }

  // epilogue: normalize, write bf16
#pragma unroll
  for (int r = 0; r < 4; ++r) {
    float inv = 1.0f / l_s[r];
    size_t row = rowQ0 + w * 16 + lg * 4 + r;
#pragma unroll
    for (int ct8 = 0; ct8 < 8; ++ct8)
      out[row * 2048 + h * 128 + ct8 * 16 + lr] = f2bf(o_acc[ct8][r] * inv);
  }
}

// ---------------- launch ----------------

extern "C" void kernel_launch(void* const* d_in, const int* in_sizes, int n_in,
                              void* d_out, int out_size, void* d_ws,
                              size_t ws_size, hipStream_t stream) {
  const float* x  = (const float*)d_in[0];
  const float* wq = (const float*)d_in[2];
  const float* bq = (const float*)d_in[3];
  const float* wk = (const float*)d_in[4];
  const float* bk = (const float*)d_in[5];
  const float* wv = (const float*)d_in[6];
  const float* bv = (const float*)d_in[7];
  const float* wo = (const float*)d_in[8];
  const float* bo = (const float*)d_in[9];
  float* out = (float*)d_out;

  char* ws = (char*)d_ws;
  unsigned short* xb    = (unsigned short*)(ws);                       // 16.8MB [4096][2048] (reused as attn out)
  unsigned short* wqkvT = (unsigned short*)(ws + 16777216);            // 9.4MB  [2304][2048]
  unsigned short* woT   = (unsigned short*)(ws + 26214400);            // 8.4MB  [2048][2048]
  unsigned short* qkvb  = (unsigned short*)(ws + 34603008);            // 18.9MB [4096][2304]
  float*          biasq = (float*)(ws + 53477376);                     // 9.2KB

  k_convert<<<4096, 256, 0, stream>>>(x, xb, 1048576);
  k_transpose<<<dim3(64, 64), dim3(32, 8), 0, stream>>>(wq, wqkvT, 2048, 2048);
  k_transpose<<<dim3(4, 64),  dim3(32, 8), 0, stream>>>(wk, wqkvT + (size_t)2048 * 2048, 2048, 128);
  k_transpose<<<dim3(4, 64),  dim3(32, 8), 0, stream>>>(wv, wqkvT + (size_t)2176 * 2048, 2048, 128);
  k_transpose<<<dim3(64, 64), dim3(32, 8), 0, stream>>>(wo, woT, 2048, 2048);
  k_bias_concat<<<9, 256, 0, stream>>>(bq, bk, bv, biasq);

  k_gemm<false><<<dim3(18, 32), 256, 0, stream>>>(xb, wqkvT, biasq, qkvb, 4096, 2304, 2048);
  k_attn<<<512, 512, 0, stream>>>(qkvb, xb);
  k_gemm<true><<<dim3(16, 32), 256, 0, stream>>>(xb, woT, bo, out, 4096, 2048, 2048);
}

// Round 3
// 374.963 us; speedup vs baseline: 1.1303x; 1.1063x over previous
//
#include <hip/hip_runtime.h>

typedef __attribute__((ext_vector_type(8))) short bf16x8;
typedef __attribute__((ext_vector_type(4))) float f32x4;

#define GLD_LDS16(g, l)                                                        \
  __builtin_amdgcn_global_load_lds(                                            \
      (const __attribute__((address_space(1))) void*)(g),                      \
      (__attribute__((address_space(3))) void*)(l), 16, 0, 0)

__device__ __forceinline__ f32x4 mfma_bf16(bf16x8 a, bf16x8 b, f32x4 c) {
  return __builtin_amdgcn_mfma_f32_16x16x32_bf16(a, b, c, 0, 0, 0);
}

__device__ __forceinline__ unsigned short f2bf(float f) {
  union { float f; unsigned int u; } a;
  a.f = f;
  unsigned int u = a.u;
  unsigned int r = (u + 0x7fffu + ((u >> 16) & 1u)) >> 16;
  return (unsigned short)r;
}

// ---------------- prep kernels ----------------

__global__ void k_convert(const float* __restrict__ in,
                          unsigned short* __restrict__ out, int n8) {
  int i = blockIdx.x * 256 + threadIdx.x;
  if (i >= n8) return;
  const float4* p = reinterpret_cast<const float4*>(in) + (size_t)i * 2;
  float4 a = p[0], b = p[1];
  union { unsigned short u[8]; uint4 v; } pk;
  pk.u[0] = f2bf(a.x); pk.u[1] = f2bf(a.y); pk.u[2] = f2bf(a.z); pk.u[3] = f2bf(a.w);
  pk.u[4] = f2bf(b.x); pk.u[5] = f2bf(b.y); pk.u[6] = f2bf(b.z); pk.u[7] = f2bf(b.w);
  reinterpret_cast<uint4*>(out)[i] = pk.v;
}

// out[c][r] = in[r][c], in: [R][C] f32, out: [C][R] bf16
__global__ void k_transpose(const float* __restrict__ in,
                            unsigned short* __restrict__ out, int R, int C) {
  __shared__ float tile[32][33];
  int c0 = blockIdx.x * 32, r0 = blockIdx.y * 32;
  int tx = threadIdx.x, ty = threadIdx.y;
#pragma unroll
  for (int j = 0; j < 4; ++j)
    tile[ty + j * 8][tx] = in[(size_t)(r0 + ty + j * 8) * C + (c0 + tx)];
  __syncthreads();
#pragma unroll
  for (int j = 0; j < 4; ++j)
    out[(size_t)(c0 + ty + j * 8) * R + (r0 + tx)] = f2bf(tile[tx][ty + j * 8]);
}

__global__ void k_bias_concat(const float* __restrict__ bq,
                              const float* __restrict__ bk,
                              const float* __restrict__ bv,
                              float* __restrict__ o) {
  int i = blockIdx.x * 256 + threadIdx.x;
  if (i < 2048) o[i] = bq[i];
  else if (i < 2176) o[i] = bk[i - 2048];
  else if (i < 2304) o[i] = bv[i - 2176];
}

// ---------------- GEMM: C[M][N] = A[M][K] * Bt[N][K]^T + bias ----------------

template <bool OUT_F32>
__global__ __launch_bounds__(256, 2) void k_gemm(
    const unsigned short* __restrict__ A, const unsigned short* __restrict__ Bt,
    const float* __restrict__ bias, void* __restrict__ Cp, int M, int N, int K) {
  __shared__ __align__(16) unsigned short lda[128 * 32];
  __shared__ __align__(16) unsigned short ldb[128 * 32];
  const int t = threadIdx.x;
  const int l = t & 63;
  const int w = t >> 6;
  const int wr = w >> 1, wc = w & 1;
  const int lr = l & 15, lg = l >> 4;
  const int m0 = blockIdx.y * 128, n0 = blockIdx.x * 128;

  f32x4 acc[4][4] = {};

  for (int kt = 0; kt < K; kt += 32) {
#pragma unroll
    for (int c = 0; c < 2; ++c) {
      int idx = t * 8 + c * 2048;
      int row = idx >> 5, col = idx & 31;
      GLD_LDS16(A + (size_t)(m0 + row) * K + kt + col, lda + w * 512 + c * 2048);
      GLD_LDS16(Bt + (size_t)(n0 + row) * K + kt + col, ldb + w * 512 + c * 2048);
    }
    __syncthreads();
    bf16x8 af[4], bfr[4];
#pragma unroll
    for (int i = 0; i < 4; ++i)
      af[i] = *reinterpret_cast<const bf16x8*>(lda + (wr * 64 + i * 16 + lr) * 32 + lg * 8);
#pragma unroll
    for (int j = 0; j < 4; ++j)
      bfr[j] = *reinterpret_cast<const bf16x8*>(ldb + (wc * 64 + j * 16 + lr) * 32 + lg * 8);
#pragma unroll
    for (int i = 0; i < 4; ++i)
#pragma unroll
      for (int j = 0; j < 4; ++j)
        acc[i][j] = mfma_bf16(af[i], bfr[j], acc[i][j]);
    __syncthreads();
  }

#pragma unroll
  for (int j = 0; j < 4; ++j) {
    int col = n0 + wc * 64 + j * 16 + lr;
    float bv = bias[col];
#pragma unroll
    for (int i = 0; i < 4; ++i) {
      int rowb = m0 + wr * 64 + i * 16 + lg * 4;
#pragma unroll
      for (int r = 0; r < 4; ++r) {
        float v = acc[i][j][r] + bv;
        if (OUT_F32)
          reinterpret_cast<float*>(Cp)[(size_t)(rowb + r) * N + col] = v;
        else
          reinterpret_cast<unsigned short*>(Cp)[(size_t)(rowb + r) * N + col] = f2bf(v);
      }
    }
  }
}

// ---------------- flash attention (8 waves, swapped QK^T, in-lane softmax) ----
// qkv: [4096][2304] bf16 (Q: cols h*128+d, K: 2048+d, V: 2176+d)
// out: [4096][2048] bf16, layout [b*2048+s][h*128+d]

__global__ __launch_bounds__(512, 4) void k_attn(
    const unsigned short* __restrict__ qkv, unsigned short* __restrict__ out) {
  __shared__ __align__(16) unsigned short k_lds[2][64 * 128];  // xor-swizzled 16B units
  __shared__ __align__(16) unsigned short v_lds[128 * 68];     // V^T, padded 68
  __shared__ __align__(16) unsigned short p_lds[128 * 72];     // P, padded 72

  const int t = threadIdx.x, l = t & 63, w = t >> 6;
  const int lr = l & 15, lg = l >> 4;
  const int bid = blockIdx.x;
  const int qt = bid & 15, h = (bid >> 4) & 15, b = bid >> 8;
  const size_t rowQ0 = (size_t)b * 2048 + qt * 128;
  const size_t rowK0 = (size_t)b * 2048;

  // Q fragments direct from global (one-time): wave w owns q-rows w*16..w*16+15
  bf16x8 qf[4];
  {
    const unsigned short* qrow = qkv + (rowQ0 + w * 16 + lr) * 2304 + h * 128;
#pragma unroll
    for (int kd = 0; kd < 4; ++kd)
      qf[kd] = *reinterpret_cast<const bf16x8*>(qrow + kd * 32 + lg * 8);
  }

  // prologue: stage K chunk 0 (swizzled source -> linear LDS), V chunk 0
#pragma unroll
  for (int c = 0; c < 2; ++c) {
    int f16 = t + c * 512;
    int row = f16 >> 4;
    int col16 = (f16 & 15) ^ (row & 7);
    GLD_LDS16(qkv + (rowK0 + row) * 2304 + 2048 + col16 * 8,
              &k_lds[0][0] + w * 512 + c * 4096);
  }
  bf16x8 vst[2];
#pragma unroll
  for (int c = 0; c < 2; ++c)
    vst[c] = *reinterpret_cast<const bf16x8*>(
        qkv + (rowK0 + l) * 2304 + 2176 + w * 16 + c * 8);
#pragma unroll
  for (int c = 0; c < 2; ++c)
#pragma unroll
    for (int e = 0; e < 8; ++e)
      v_lds[(w * 16 + c * 8 + e) * 68 + l] = (unsigned short)vst[c][e];
  __syncthreads();

  f32x4 o_acc[8] = {};
  // per-lane scalars for q-row (w*16 + lr), replicated across the 4 lg lanes
  float m_s = -1e30f, l_s = 0.f;

  const float C_SM = 0.08838834764831845f * 1.4426950408889634f;

  for (int kc = 0; kc < 32; ++kc) {
    const int cur = kc & 1;
    const unsigned short* kl = &k_lds[cur][0];

    if (kc < 31) {
      // issue next K chunk into other buffer (latency hides under compute)
#pragma unroll
      for (int c = 0; c < 2; ++c) {
        int f16 = t + c * 512;
        int row = f16 >> 4;
        int col16 = (f16 & 15) ^ (row & 7);
        GLD_LDS16(qkv + (rowK0 + (kc + 1) * 64 + row) * 2304 + 2048 + col16 * 8,
                  &k_lds[cur ^ 1][0] + w * 512 + c * 4096);
      }
      // issue next V chunk into regs (ds_write after barrier)
#pragma unroll
      for (int c = 0; c < 2; ++c)
        vst[c] = *reinterpret_cast<const bf16x8*>(
            qkv + (rowK0 + (kc + 1) * 64 + l) * 2304 + 2176 + w * 16 + c * 8);
    }

    // S^T = K Q^T (swapped): sf[ctK][r] = S[q = w*16+lr][k = kc*64 + ctK*16 + lg*4 + r]
    f32x4 sf[4];
#pragma unroll
    for (int ctK = 0; ctK < 4; ++ctK) {
      f32x4 s = {0.f, 0.f, 0.f, 0.f};
#pragma unroll
      for (int kd = 0; kd < 4; ++kd) {
        int row = ctK * 16 + lr;
        int u = (kd * 4 + lg) ^ (row & 7);
        bf16x8 kf = *reinterpret_cast<const bf16x8*>(kl + row * 128 + u * 8);
        s = mfma_bf16(kf, qf[kd], s);
      }
      sf[ctK] = s;
    }

    // online softmax: row stats live in-lane (row = w*16+lr)
    float vmax;
    {
      f32x4 m4 = sf[0];
#pragma unroll
      for (int ctK = 1; ctK < 4; ++ctK) {
        m4[0] = fmaxf(m4[0], sf[ctK][0]); m4[1] = fmaxf(m4[1], sf[ctK][1]);
        m4[2] = fmaxf(m4[2], sf[ctK][2]); m4[3] = fmaxf(m4[3], sf[ctK][3]);
      }
      vmax = fmaxf(fmaxf(m4[0], m4[1]), fmaxf(m4[2], m4[3]));
      vmax = fmaxf(vmax, __shfl_xor(vmax, 16));
      vmax = fmaxf(vmax, __shfl_xor(vmax, 32));
    }
    if (!__all(vmax <= m_s)) {  // skip rescale when no row in wave grew
      float newm = fmaxf(m_s, vmax);
      float alpha = __builtin_amdgcn_exp2f((m_s - newm) * C_SM);
      m_s = newm;
      l_s *= alpha;
#pragma unroll
      for (int r = 0; r < 4; ++r) {
        float a_r = __shfl(alpha, lg * 4 + r);  // alpha of o-row lg*4+r
#pragma unroll
        for (int ct8 = 0; ct8 < 8; ++ct8) o_acc[ct8][r] *= a_r;
      }
    }
    {
      float psum = 0.f;
#pragma unroll
      for (int ctK = 0; ctK < 4; ++ctK) {
#pragma unroll
        for (int r = 0; r < 4; ++r) {
          float p = __builtin_amdgcn_exp2f((sf[ctK][r] - m_s) * C_SM);
          sf[ctK][r] = p;
          psum += p;
        }
      }
      psum += __shfl_xor(psum, 16);
      psum += __shfl_xor(psum, 32);
      l_s += psum;
    }

    // write P: lane owns 4 consecutive k's per tile -> conflict-free b64 writes
#pragma unroll
    for (int ctK = 0; ctK < 4; ++ctK) {
      union { unsigned short u[4]; uint2 v; } pk;
#pragma unroll
      for (int r = 0; r < 4; ++r) pk.u[r] = f2bf(sf[ctK][r]);
      *reinterpret_cast<uint2*>(p_lds + (w * 16 + lr) * 72 + ctK * 16 + lg * 4) = pk.v;
    }

    // O += P V  (p_lds slab is wave-private; no barrier needed)
#pragma unroll
    for (int ks = 0; ks < 2; ++ks) {
      bf16x8 pf = *reinterpret_cast<const bf16x8*>(
          p_lds + (w * 16 + lr) * 72 + ks * 32 + lg * 8);
#pragma unroll
      for (int ct8 = 0; ct8 < 8; ++ct8) {
        bf16x8 vf = *reinterpret_cast<const bf16x8*>(
            v_lds + (ct8 * 16 + lr) * 68 + ks * 32 + lg * 8);
        o_acc[ct8] = mfma_bf16(pf, vf, o_acc[ct8]);
      }
    }

    __syncthreads();  // everyone done reading v_lds (also drains vmcnt: K-next in)
    if (kc < 31) {
#pragma unroll
      for (int c = 0; c < 2; ++c)
#pragma unroll
        for (int e = 0; e < 8; ++e)
          v_lds[(w * 16 + c * 8 + e) * 68 + l] = (unsigned short)vst[c][e];
    }
    __syncthreads();  // v_lds (and k_lds[nxt]) ready
  }

  // epilogue: normalize, write bf16 (l for o-row lg*4+r lives in lane lg*4+r)
  float inv = 1.0f / l_s;
  float inv4[4];
#pragma unroll
  for (int r = 0; r < 4; ++r) inv4[r] = __shfl(inv, lg * 4 + r);
#pragma unroll
  for (int r = 0; r < 4; ++r) {
    size_t row = rowQ0 + w * 16 + lg * 4 + r;
#pragma unroll
    for (int ct8 = 0; ct8 < 8; ++ct8)
      out[row * 2048 + h * 128 + ct8 * 16 + lr] = f2bf(o_acc[ct8][r] * inv4[r]);
  }
}

// ---------------- launch ----------------

extern "C" void kernel_launch(void* const* d_in, const int* in_sizes, int n_in,
                              void* d_out, int out_size, void* d_ws,
                              size_t ws_size, hipStream_t stream) {
  const float* x  = (const float*)d_in[0];
  const float* wq = (const float*)d_in[2];
  const float* bq = (const float*)d_in[3];
  const float* wk = (const float*)d_in[4];
  const float* bk = (const float*)d_in[5];
  const float* wv = (const float*)d_in[6];
  const float* bv = (const float*)d_in[7];
  const float* wo = (const float*)d_in[8];
  const float* bo = (const float*)d_in[9];
  float* out = (float*)d_out;

  char* ws = (char*)d_ws;
  unsigned short* xb    = (unsigned short*)(ws);                       // 16.8MB [4096][2048] (reused as attn out)
  unsigned short* wqkvT = (unsigned short*)(ws + 16777216);            // 9.4MB  [2304][2048]
  unsigned short* woT   = (unsigned short*)(ws + 26214400);            // 8.4MB  [2048][2048]
  unsigned short* qkvb  = (unsigned short*)(ws + 34603008);            // 18.9MB [4096][2304]
  float*          biasq = (float*)(ws + 53477376);                     // 9.2KB

  k_convert<<<4096, 256, 0, stream>>>(x, xb, 1048576);
  k_transpose<<<dim3(64, 64), dim3(32, 8), 0, stream>>>(wq, wqkvT, 2048, 2048);
  k_transpose<<<dim3(4, 64),  dim3(32, 8), 0, stream>>>(wk, wqkvT + (size_t)2048 * 2048, 2048, 128);
  k_transpose<<<dim3(4, 64),  dim3(32, 8), 0, stream>>>(wv, wqkvT + (size_t)2176 * 2048, 2048, 128);
  k_transpose<<<dim3(64, 64), dim3(32, 8), 0, stream>>>(wo, woT, 2048, 2048);
  k_bias_concat<<<9, 256, 0, stream>>>(bq, bk, bv, biasq);

  k_gemm<false><<<dim3(18, 32), 256, 0, stream>>>(xb, wqkvT, biasq, qkvb, 4096, 2304, 2048);
  k_attn<<<512, 512, 0, stream>>>(qkvb, xb);
  k_gemm<true><<<dim3(16, 32), 256, 0, stream>>>(xb, woT, bo, out, 4096, 2048, 2048);
}

// Round 7
// 362.835 us; speedup vs baseline: 1.1681x; 1.0334x over previous
//
#include <hip/hip_runtime.h>

typedef __attribute__((ext_vector_type(8))) short bf16x8;
typedef __attribute__((ext_vector_type(4))) float f32x4;

#define GLD_LDS16(g, l)                                                        \
  __builtin_amdgcn_global_load_lds(                                            \
      (const __attribute__((address_space(1))) void*)(g),                      \
      (__attribute__((address_space(3))) void*)(l), 16, 0, 0)

__device__ __forceinline__ f32x4 mfma_bf16(bf16x8 a, bf16x8 b, f32x4 c) {
  return __builtin_amdgcn_mfma_f32_16x16x32_bf16(a, b, c, 0, 0, 0);
}

__device__ __forceinline__ unsigned short f2bf(float f) {
  union { float f; unsigned int u; } a;
  a.f = f;
  unsigned int u = a.u;
  unsigned int r = (u + 0x7fffu + ((u >> 16) & 1u)) >> 16;
  return (unsigned short)r;
}

// ---------------- prep kernels ----------------

__global__ void k_convert(const float* __restrict__ in,
                          unsigned short* __restrict__ out, int n8) {
  int i = blockIdx.x * 256 + threadIdx.x;
  if (i >= n8) return;
  const float4* p = reinterpret_cast<const float4*>(in) + (size_t)i * 2;
  float4 a = p[0], b = p[1];
  union { unsigned short u[8]; uint4 v; } pk;
  pk.u[0] = f2bf(a.x); pk.u[1] = f2bf(a.y); pk.u[2] = f2bf(a.z); pk.u[3] = f2bf(a.w);
  pk.u[4] = f2bf(b.x); pk.u[5] = f2bf(b.y); pk.u[6] = f2bf(b.z); pk.u[7] = f2bf(b.w);
  reinterpret_cast<uint4*>(out)[i] = pk.v;
}

// out[c][r] = in[r][c], in: [R][C] f32, out: [C][R] bf16
__global__ void k_transpose(const float* __restrict__ in,
                            unsigned short* __restrict__ out, int R, int C) {
  __shared__ float tile[32][33];
  int c0 = blockIdx.x * 32, r0 = blockIdx.y * 32;
  int tx = threadIdx.x, ty = threadIdx.y;
#pragma unroll
  for (int j = 0; j < 4; ++j)
    tile[ty + j * 8][tx] = in[(size_t)(r0 + ty + j * 8) * C + (c0 + tx)];
  __syncthreads();
#pragma unroll
  for (int j = 0; j < 4; ++j)
    out[(size_t)(c0 + ty + j * 8) * R + (r0 + tx)] = f2bf(tile[tx][ty + j * 8]);
}

// vT[b][d][swz(k)] = V[b][k][d]; swizzle on 8-elem units within each 64-k chunk
__global__ void k_transpose_v(const unsigned short* __restrict__ qkv,
                              unsigned short* __restrict__ vT) {
  __shared__ unsigned short tile[32][33];
  int k0 = blockIdx.x * 32, d0 = blockIdx.y * 32, b = blockIdx.z;
  int tx = threadIdx.x, ty = threadIdx.y;
  const unsigned short* src = qkv + ((size_t)b * 2048 + k0) * 2304 + 2176 + d0;
#pragma unroll
  for (int j = 0; j < 4; ++j)
    tile[ty + j * 8][tx] = src[(size_t)(ty + j * 8) * 2304 + tx];
  __syncthreads();
#pragma unroll
  for (int j = 0; j < 4; ++j) {
    int d = d0 + ty + j * 8;
    int k = k0 + tx;
    int ks = (k & ~63) | (((((k >> 3) & 7) ^ (d & 7)) << 3)) | (k & 7);
    vT[(size_t)b * 262144 + (size_t)d * 2048 + ks] = tile[tx][ty + j * 8];
  }
}

__global__ void k_bias_concat(const float* __restrict__ bq,
                              const float* __restrict__ bk,
                              const float* __restrict__ bv,
                              float* __restrict__ o) {
  int i = blockIdx.x * 256 + threadIdx.x;
  if (i < 2048) o[i] = bq[i];
  else if (i < 2176) o[i] = bk[i - 2048];
  else if (i < 2304) o[i] = bv[i - 2176];
}

// ---------------- GEMM: C[M][N] = A[M][K] * Bt[N][K]^T + bias ----------------
// 2-phase: stage(next) issued before compute(cur); single barrier per K-step.

template <bool OUT_F32>
__global__ __launch_bounds__(256, 2) void k_gemm(
    const unsigned short* __restrict__ A, const unsigned short* __restrict__ Bt,
    const float* __restrict__ bias, void* __restrict__ Cp, int M, int N, int K) {
  __shared__ __align__(16) unsigned short lda[2][128 * 32];
  __shared__ __align__(16) unsigned short ldb[2][128 * 32];
  const int t = threadIdx.x;
  const int l = t & 63;
  const int w = t >> 6;
  const int wr = w >> 1, wc = w & 1;
  const int lr = l & 15, lg = l >> 4;
  const int m0 = blockIdx.y * 128, n0 = blockIdx.x * 128;

  f32x4 acc[4][4] = {};

  // prologue: stage kt=0 into buffer 0
#pragma unroll
  for (int c = 0; c < 2; ++c) {
    int idx = t * 8 + c * 2048;
    int row = idx >> 5, col = idx & 31;
    GLD_LDS16(A + (size_t)(m0 + row) * K + col, &lda[0][0] + w * 512 + c * 2048);
    GLD_LDS16(Bt + (size_t)(n0 + row) * K + col, &ldb[0][0] + w * 512 + c * 2048);
  }
  __syncthreads();

  int cur = 0;
  for (int kt = 32; kt < K; kt += 32) {
    // stage next tile into other buffer (flies under the MFMAs below)
#pragma unroll
    for (int c = 0; c < 2; ++c) {
      int idx = t * 8 + c * 2048;
      int row = idx >> 5, col = idx & 31;
      GLD_LDS16(A + (size_t)(m0 + row) * K + kt + col,
                &lda[cur ^ 1][0] + w * 512 + c * 2048);
      GLD_LDS16(Bt + (size_t)(n0 + row) * K + kt + col,
                &ldb[cur ^ 1][0] + w * 512 + c * 2048);
    }
    bf16x8 af[4], bfr[4];
#pragma unroll
    for (int i = 0; i < 4; ++i)
      af[i] = *reinterpret_cast<const bf16x8*>(&lda[cur][0] + (wr * 64 + i * 16 + lr) * 32 + lg * 8);
#pragma unroll
    for (int j = 0; j < 4; ++j)
      bfr[j] = *reinterpret_cast<const bf16x8*>(&ldb[cur][0] + (wc * 64 + j * 16 + lr) * 32 + lg * 8);
#pragma unroll
    for (int i = 0; i < 4; ++i)
#pragma unroll
      for (int j = 0; j < 4; ++j)
        acc[i][j] = mfma_bf16(af[i], bfr[j], acc[i][j]);
    __syncthreads();  // drains vmcnt (next buf ready) + protects cur buf reuse
    cur ^= 1;
  }
  {
    bf16x8 af[4], bfr[4];
#pragma unroll
    for (int i = 0; i < 4; ++i)
      af[i] = *reinterpret_cast<const bf16x8*>(&lda[cur][0] + (wr * 64 + i * 16 + lr) * 32 + lg * 8);
#pragma unroll
    for (int j = 0; j < 4; ++j)
      bfr[j] = *reinterpret_cast<const bf16x8*>(&ldb[cur][0] + (wc * 64 + j * 16 + lr) * 32 + lg * 8);
#pragma unroll
    for (int i = 0; i < 4; ++i)
#pragma unroll
      for (int j = 0; j < 4; ++j)
        acc[i][j] = mfma_bf16(af[i], bfr[j], acc[i][j]);
  }

#pragma unroll
  for (int j = 0; j < 4; ++j) {
    int col = n0 + wc * 64 + j * 16 + lr;
    float bv = bias[col];
#pragma unroll
    for (int i = 0; i < 4; ++i) {
      int rowb = m0 + wr * 64 + i * 16 + lg * 4;
#pragma unroll
      for (int r = 0; r < 4; ++r) {
        float v = acc[i][j][r] + bv;
        if (OUT_F32)
          reinterpret_cast<float*>(Cp)[(size_t)(rowb + r) * N + col] = v;
        else
          reinterpret_cast<unsigned short*>(Cp)[(size_t)(rowb + r) * N + col] = f2bf(v);
      }
    }
  }
}

// ---------------- flash attention ----------------
// qkv: [4096][2304] bf16; vT: [2][128][2048] bf16 (k pre-swizzled per 64-chunk)
// out: [4096][2048] bf16, layout [b*2048+s][h*128+d]
// K dbuf + V dbuf via global_load_lds; P swizzled; 1 barrier per chunk.

__global__ __launch_bounds__(512, 4) void k_attn(
    const unsigned short* __restrict__ qkv,
    const unsigned short* __restrict__ vT,
    unsigned short* __restrict__ out) {
  __shared__ __align__(16) unsigned short k_lds[2][64 * 128];  // 2x16KB, swizzled
  __shared__ __align__(16) unsigned short v_lds[2][128 * 64];  // 2x16KB, swizzled (from vT)
  __shared__ __align__(16) unsigned short p_lds[128 * 64];     // 16KB, swizzled

  const int t = threadIdx.x, l = t & 63, w = t >> 6;
  const int lr = l & 15, lg = l >> 4;
  const int bid = blockIdx.x;
  const int qt = bid & 15, h = (bid >> 4) & 15, b = bid >> 8;
  const size_t rowQ0 = (size_t)b * 2048 + qt * 128;
  const size_t rowK0 = (size_t)b * 2048;
  const unsigned short* vTb = vT + (size_t)b * 262144;

  // Q fragments direct from global (one-time): wave w owns q-rows w*16..w*16+15
  bf16x8 qf[4];
  {
    const unsigned short* qrow = qkv + (rowQ0 + w * 16 + lr) * 2304 + h * 128;
#pragma unroll
    for (int kd = 0; kd < 4; ++kd)
      qf[kd] = *reinterpret_cast<const bf16x8*>(qrow + kd * 32 + lg * 8);
  }

  // prologue: stage chunk 0 (K swizzled-source, V already swizzled in vT)
#pragma unroll
  for (int c = 0; c < 2; ++c) {
    int f16 = t + c * 512;
    int row = f16 >> 4;
    int col16 = (f16 & 15) ^ (row & 7);
    GLD_LDS16(qkv + (rowK0 + row) * 2304 + 2048 + col16 * 8,
              &k_lds[0][0] + w * 512 + c * 4096);
  }
#pragma unroll
  for (int c = 0; c < 2; ++c) {
    int unit = t + c * 512;
    int d = unit >> 3, u = unit & 7;
    GLD_LDS16(vTb + (size_t)d * 2048 + u * 8,
              &v_lds[0][0] + w * 512 + c * 4096);
  }
  __syncthreads();

  f32x4 o_acc[8] = {};
  float m_s = -1e30f, l_s = 0.f;  // per-lane stats for q-row (w*16+lr)

  const float C_SM = 0.08838834764831845f * 1.4426950408889634f;

  for (int kc = 0; kc < 32; ++kc) {
    const int cur = kc & 1;
    const unsigned short* kl = &k_lds[cur][0];
    const unsigned short* vl = &v_lds[cur][0];

    if (kc < 31) {
#pragma unroll
      for (int c = 0; c < 2; ++c) {
        int f16 = t + c * 512;
        int row = f16 >> 4;
        int col16 = (f16 & 15) ^ (row & 7);
        GLD_LDS16(qkv + (rowK0 + (kc + 1) * 64 + row) * 2304 + 2048 + col16 * 8,
                  &k_lds[cur ^ 1][0] + w * 512 + c * 4096);
      }
#pragma unroll
      for (int c = 0; c < 2; ++c) {
        int unit = t + c * 512;
        int d = unit >> 3, u = unit & 7;
        GLD_LDS16(vTb + (size_t)d * 2048 + (kc + 1) * 64 + u * 8,
                  &v_lds[cur ^ 1][0] + w * 512 + c * 4096);
      }
    }

    // S^T = K Q^T: sf[ctK][r] = S[q=w*16+lr][k = kc*64 + ctK*16 + lg*4 + r]
    f32x4 sf[4];
    __builtin_amdgcn_s_setprio(1);
#pragma unroll
    for (int ctK = 0; ctK < 4; ++ctK) {
      f32x4 s = {0.f, 0.f, 0.f, 0.f};
#pragma unroll
      for (int kd = 0; kd < 4; ++kd) {
        int row = ctK * 16 + lr;
        int u = (kd * 4 + lg) ^ (row & 7);
        bf16x8 kf = *reinterpret_cast<const bf16x8*>(kl + row * 128 + u * 8);
        s = mfma_bf16(kf, qf[kd], s);
      }
      sf[ctK] = s;
    }
    __builtin_amdgcn_s_setprio(0);

    // online softmax, in-lane row stats
    float vmax;
    {
      f32x4 m4 = sf[0];
#pragma unroll
      for (int ctK = 1; ctK < 4; ++ctK) {
        m4[0] = fmaxf(m4[0], sf[ctK][0]); m4[1] = fmaxf(m4[1], sf[ctK][1]);
        m4[2] = fmaxf(m4[2], sf[ctK][2]); m4[3] = fmaxf(m4[3], sf[ctK][3]);
      }
      vmax = fmaxf(fmaxf(m4[0], m4[1]), fmaxf(m4[2], m4[3]));
      vmax = fmaxf(vmax, __shfl_xor(vmax, 16));
      vmax = fmaxf(vmax, __shfl_xor(vmax, 32));
    }
    if (!__all(vmax <= m_s)) {
      float newm = fmaxf(m_s, vmax);
      float alpha = __builtin_amdgcn_exp2f((m_s - newm) * C_SM);
      m_s = newm;
      l_s *= alpha;
#pragma unroll
      for (int r = 0; r < 4; ++r) {
        float a_r = __shfl(alpha, lg * 4 + r);
#pragma unroll
        for (int ct8 = 0; ct8 < 8; ++ct8) o_acc[ct8][r] *= a_r;
      }
    }
    {
      float psum = 0.f;
#pragma unroll
      for (int ctK = 0; ctK < 4; ++ctK) {
#pragma unroll
        for (int r = 0; r < 4; ++r) {
          float p = __builtin_amdgcn_exp2f((sf[ctK][r] - m_s) * C_SM);
          sf[ctK][r] = p;
          psum += p;
        }
      }
      psum += __shfl_xor(psum, 16);
      psum += __shfl_xor(psum, 32);
      l_s += psum;
    }

    // write P (wave-private, swizzled): P[q=w*16+lr][k = ctK*16+lg*4+r]
#pragma unroll
    for (int ctK = 0; ctK < 4; ++ctK) {
      union { unsigned short u[4]; uint2 v; } pk;
#pragma unroll
      for (int r = 0; r < 4; ++r) pk.u[r] = f2bf(sf[ctK][r]);
      *reinterpret_cast<uint2*>(
          p_lds + (w * 16 + lr) * 64 + ((ctK * 16 + lg * 4) ^ ((lr & 7) << 3))) = pk.v;
    }

    // O += P V (p slab wave-private -> no barrier between write and read)
    __builtin_amdgcn_s_setprio(1);
#pragma unroll
    for (int ks = 0; ks < 2; ++ks) {
      bf16x8 pf = *reinterpret_cast<const bf16x8*>(
          p_lds + (w * 16 + lr) * 64 + ((ks * 32 + lg * 8) ^ ((lr & 7) << 3)));
#pragma unroll
      for (int ct8 = 0; ct8 < 8; ++ct8) {
        bf16x8 vf = *reinterpret_cast<const bf16x8*>(
            vl + (ct8 * 16 + lr) * 64 + (((ks * 4 + lg) ^ (lr & 7)) * 8));
        o_acc[ct8] = mfma_bf16(pf, vf, o_acc[ct8]);
      }
    }
    __builtin_amdgcn_s_setprio(0);

    __syncthreads();  // drains vmcnt (next K/V staged) + protects cur bufs
  }

  // epilogue: normalize, write bf16
  float inv = 1.0f / l_s;
  float inv4[4];
#pragma unroll
  for (int r = 0; r < 4; ++r) inv4[r] = __shfl(inv, lg * 4 + r);
#pragma unroll
  for (int r = 0; r < 4; ++r) {
    size_t row = rowQ0 + w * 16 + lg * 4 + r;
#pragma unroll
    for (int ct8 = 0; ct8 < 8; ++ct8)
      out[row * 2048 + h * 128 + ct8 * 16 + lr] = f2bf(o_acc[ct8][r] * inv4[r]);
  }
}

// ---------------- launch ----------------

extern "C" void kernel_launch(void* const* d_in, const int* in_sizes, int n_in,
                              void* d_out, int out_size, void* d_ws,
                              size_t ws_size, hipStream_t stream) {
  const float* x  = (const float*)d_in[0];
  const float* wq = (const float*)d_in[2];
  const float* bq = (const float*)d_in[3];
  const float* wk = (const float*)d_in[4];
  const float* bk = (const float*)d_in[5];
  const float* wv = (const float*)d_in[6];
  const float* bv = (const float*)d_in[7];
  const float* wo = (const float*)d_in[8];
  const float* bo = (const float*)d_in[9];
  float* out = (float*)d_out;

  char* ws = (char*)d_ws;
  unsigned short* xb    = (unsigned short*)(ws);                       // 16.8MB [4096][2048] (reused as attn out)
  unsigned short* wqkvT = (unsigned short*)(ws + 16777216);            // 9.4MB  [2304][2048]
  unsigned short* woT   = (unsigned short*)(ws + 26214400);            // 8.4MB  [2048][2048]
  unsigned short* qkvb  = (unsigned short*)(ws + 34603008);            // 18.9MB [4096][2304]
  float*          biasq = (float*)(ws + 53477376);                     // 9.2KB
  unsigned short* vTb   = (unsigned short*)(ws + 53486592);            // 1.0MB  [2][128][2048]

  k_convert<<<4096, 256, 0, stream>>>(x, xb, 1048576);
  k_transpose<<<dim3(64, 64), dim3(32, 8), 0, stream>>>(wq, wqkvT, 2048, 2048);
  k_transpose<<<dim3(4, 64),  dim3(32, 8), 0, stream>>>(wk, wqkvT + (size_t)2048 * 2048, 2048, 128);
  k_transpose<<<dim3(4, 64),  dim3(32, 8), 0, stream>>>(wv, wqkvT + (size_t)2176 * 2048, 2048, 128);
  k_transpose<<<dim3(64, 64), dim3(32, 8), 0, stream>>>(wo, woT, 2048, 2048);
  k_bias_concat<<<9, 256, 0, stream>>>(bq, bk, bv, biasq);

  k_gemm<false><<<dim3(18, 32), 256, 0, stream>>>(xb, wqkvT, biasq, qkvb, 4096, 2304, 2048);
  k_transpose_v<<<dim3(64, 4, 2), dim3(32, 8), 0, stream>>>(qkvb, vTb);
  k_attn<<<512, 512, 0, stream>>>(qkvb, vTb, xb);
  k_gemm<true><<<dim3(16, 32), 256, 0, stream>>>(xb, woT, bo, out, 4096, 2048, 2048);
}